// Round 6
// baseline (209.641 us; speedup 1.0000x reference)
//
#include <hip/hip_runtime.h>
#include <math.h>
#include <stdint.h>

#define PI_F 3.14159265358979323846f
#define HALF_PI_F 1.57079632679489662f

// Problem constants: B=32, N=200000, H=1024, W=2048
#define IMG_H 1024
#define IMG_W 2048
#define NB 4          // batches per thread
#define NBINS_T 128   // theta bins
#define NBINS_P 64    // phi bins
#define NBINS (NBINS_T * NBINS_P)

// Workspace layout (bytes):
//   0        .. 2048       : rm (288 f) | sums (32 f @ idx 288) | cnts (32 f @ 320)
//   2048     .. 34816      : hist u32[8192] (counts -> offsets -> cursors)
//   34816    .. ~435KB     : key u16[n_pts] (bin key per point, cached by hist pass)
//   1MB      .. 1MB+4MB    : pk: row-pair RGB565, u32 word[(y>>1)*2048+x] = lo:row 2p, hi:row 2p+1
//   5MB+...  .. +6.4MB     : pts: sorted points, 8 floats/pt {x,y,z,r0,r1,r2,pad,pad}
#define HIST_OFF  2048
#define KEY_OFF   34816
#define PK_OFF    (1u << 20)
#define PTS_OFF   (PK_OFF + 4u * 1024u * 1024u)

typedef float v4f __attribute__((ext_vector_type(4)));

__device__ __forceinline__ float fast_atan2f(float y, float x) {
    float ax = fabsf(x), ay = fabsf(y);
    float mx = fmaxf(ax, ay), mn = fminf(ax, ay);
    float a = __fdividef(mn, mx);
    float s = a * a;
    float r = fmaf(s, -0.01172120f, 0.05265332f);
    r = fmaf(s, r, -0.11643287f);
    r = fmaf(s, r, 0.19354346f);
    r = fmaf(s, r, -0.33262347f);
    r = fmaf(s, r, 0.99997726f);
    r = r * a;
    if (ay > ax) r = HALF_PI_F - r;
    if (x < 0.0f) r = PI_F - r;
    return copysignf(r, y);
}

__device__ __forceinline__ int dir_key(float x, float y, float z) {
    float theta = fast_atan2f(sqrtf(x * x + y * y), z);   // [0, pi]
    float phi   = fast_atan2f(y, x);                      // (-pi, pi]
    int tb = min(max((int)(theta * ((float)NBINS_T / PI_F)), 0), NBINS_T - 1);
    int pb = min(max((int)((phi + PI_F) * ((float)NBINS_P / (2.0f * PI_F))), 0), NBINS_P - 1);
    return tb * NBINS_P + pb;
}

__device__ __forceinline__ uint32_t quant565(const float* __restrict__ img, int pix) {
    float r = img[pix + 0], g = img[pix + 1], b = img[pix + 2];
    uint32_t r5 = min((uint32_t)__float2uint_rn(r * 31.0f), 31u);
    uint32_t g6 = min((uint32_t)__float2uint_rn(g * 63.0f), 63u);
    uint32_t b5 = min((uint32_t)__float2uint_rn(b * 31.0f), 31u);
    return (r5 << 11) | (g6 << 5) | b5;
}

// K1: blocks [0,4096): pack image to row-pair RGB565 (4MB).
//     blocks [4096,...): per-point bucket histogram + key cache; block 4096 also does setup.
__global__ __launch_bounds__(256) void bsl_pack_hist(
        const float* __restrict__ img, uint32_t* __restrict__ pk,
        const float* __restrict__ xyz, uint32_t* __restrict__ hist,
        uint16_t* __restrict__ key,
        const float* __restrict__ yaw, const float* __restrict__ pitch,
        const float* __restrict__ roll, float* __restrict__ rm,
        float* __restrict__ sums, float* __restrict__ cnts,
        int B, int n_pts) {
    const int bx = blockIdx.x;
    const int tid = threadIdx.x;
    if (bx < 4096) {
        int idx = bx * 256 + tid;          // word index: p*2048 + x, p in [0,512)
        int p = idx >> 11;
        int x = idx & (IMG_W - 1);
        uint32_t lo = quant565(img, ((2 * p) * IMG_W + x) * 3);
        uint32_t hi = quant565(img, ((2 * p + 1) * IMG_W + x) * 3);
        pk[idx] = lo | (hi << 16);
        return;
    }
    if (bx == 4096 && tid < 32) {
        int b = tid;
        if (b < B) {
            float cr = cosf(roll[b]),  sr = sinf(roll[b]);
            float cp = cosf(pitch[b]), sp = sinf(pitch[b]);
            float cy = cosf(yaw[b]),   sy = sinf(yaw[b]);
            float RX[9] = {1.f, 0.f, 0.f,   0.f, cr, -sr,   0.f, sr,  cr};
            float RY[9] = {cp,  0.f, sp,    0.f, 1.f, 0.f,  -sp, 0.f, cp};
            float RZ[9] = {cy, -sy, 0.f,    sy,  cy, 0.f,   0.f, 0.f, 1.f};
            float A[9], M[9];
            for (int i = 0; i < 3; ++i)
                for (int j = 0; j < 3; ++j) {
                    float s = 0.f;
                    for (int k = 0; k < 3; ++k) s += RZ[i*3+k] * RY[k*3+j];
                    A[i*3+j] = s;
                }
            for (int i = 0; i < 3; ++i)
                for (int j = 0; j < 3; ++j) {
                    float s = 0.f;
                    for (int k = 0; k < 3; ++k) s += A[i*3+k] * RX[k*3+j];
                    M[i*3+j] = s;
                }
            for (int k = 0; k < 9; ++k) rm[b*9+k] = M[k];
            sums[b] = 0.f;
            cnts[b] = 0.f;
        }
    }
    int n = (bx - 4096) * 256 + tid;
    if (n < n_pts) {
        int k = dir_key(xyz[3*n+0], xyz[3*n+1], xyz[3*n+2]);
        key[n] = (uint16_t)k;
        atomicAdd(&hist[k], 1u);
    }
}

// K2: exclusive prefix sum over 8192 bins. 256 threads, 32 bins each;
// wave-shuffle scan of partials (2 barriers total).
__global__ __launch_bounds__(256) void bsl_scan(uint32_t* __restrict__ hist) {
    const int t = threadIdx.x;
    const int lane = t & 63, wid = t >> 6;
    uint32_t local[32];
    uint32_t s = 0;
    #pragma unroll
    for (int i = 0; i < 32; ++i) { local[i] = hist[t * 32 + i]; s += local[i]; }
    // inclusive wave scan of s
    uint32_t inc = s;
    #pragma unroll
    for (int off = 1; off < 64; off <<= 1) {
        uint32_t u = __shfl_up(inc, off, 64);
        if (lane >= off) inc += u;
    }
    __shared__ uint32_t wtot[4], wpre[4];
    if (lane == 63) wtot[wid] = inc;
    __syncthreads();
    if (t == 0) {
        uint32_t r = 0;
        #pragma unroll
        for (int w = 0; w < 4; ++w) { wpre[w] = r; r += wtot[w]; }
    }
    __syncthreads();
    uint32_t run = inc - s + wpre[wid];   // exclusive prefix for this thread's chunk
    #pragma unroll
    for (int i = 0; i < 32; ++i) { uint32_t c = local[i]; hist[t * 32 + i] = run; run += c; }
}

// K3: scatter points into bucket-sorted order using cached keys (hist = cursors).
__global__ __launch_bounds__(256) void bsl_scatter(
        const float* __restrict__ xyz, const float* __restrict__ rgb,
        const uint16_t* __restrict__ key,
        uint32_t* __restrict__ hist, float* __restrict__ pts, int n_pts) {
    int n = blockIdx.x * 256 + threadIdx.x;
    if (n >= n_pts) return;
    int k = key[n];
    uint32_t pos = atomicAdd(&hist[k], 1u);
    v4f a, b2;
    a.x = xyz[3*n+0]; a.y = xyz[3*n+1]; a.z = xyz[3*n+2]; a.w = rgb[3*n+0];
    b2.x = rgb[3*n+1]; b2.y = rgb[3*n+2]; b2.z = 0.f; b2.w = 0.f;
    v4f* p = (v4f*)(pts + (size_t)pos * 8);
    p[0] = a;
    p[1] = b2;
}

__global__ __launch_bounds__(256) void bsl_main(
        const float* __restrict__ pts,
        const uint32_t* __restrict__ pk,
        const float* __restrict__ trans,
        const float* __restrict__ rm,
        float* __restrict__ sums,
        float* __restrict__ cnts,
        int n_pts) {
    const int b0 = blockIdx.y * NB;
    const int tid = threadIdx.x;
    const int n = blockIdx.x * 256 + tid;

    float accs[NB], cnl[NB];
    #pragma unroll
    for (int nb = 0; nb < NB; ++nb) { accs[nb] = 0.f; cnl[nb] = 0.f; }

    if (n < n_pts) {
        const v4f* P = (const v4f*)(pts + (size_t)n * 8);
        v4f A = __builtin_nontemporal_load(&P[0]);
        v4f Bv = __builtin_nontemporal_load(&P[1]);
        float px = A.x, py = A.y, pz = A.z;
        float r0 = A.w, r1 = Bv.x, r2 = Bv.y;

        #pragma unroll
        for (int nb = 0; nb < NB; ++nb) {
            const int b = b0 + nb;
            const float* R = rm + b * 9;        // block-uniform -> s_load
            const float* T = trans + b * 3;
            float qx = px - T[0], qy = py - T[1], qz = pz - T[2];

            float vx = R[0]*qx + R[1]*qy + R[2]*qz;
            float vy = R[3]*qx + R[4]*qy + R[5]*qz;
            float vz = R[6]*qx + R[7]*qy + R[8]*qz;

            float rxy   = sqrtf(vx*vx + vy*vy);
            float theta = fast_atan2f(rxy, vz);     // [0, pi]
            float praw  = fast_atan2f(vy, vx);      // (-pi, pi]

            // xf = 1023.5 - 1024*praw/pi ; yf = 1024*theta/pi - 0.5
            float xf = fmaf(praw,  -325.949323452f, 1023.5f);
            float yf = fmaf(theta,  325.949323452f, -0.5f);

            float x0f = floorf(xf), y0f = floorf(yf);
            float wx = xf - x0f, wy = yf - y0f;
            int x0 = (int)x0f, y0 = (int)y0f;
            int x1 = x0 + 1, y1 = y0 + 1;

            // ranges: x0 in [-1,2047], x1 in [0,2048], y0 in [-1,1023], y1 in [0,1024]
            float wx0 = (x0 >= 0)        ? (1.0f - wx) : 0.0f;
            float wx1 = (x1 <= IMG_W-1)  ? wx          : 0.0f;
            float wy0 = (y0 >= 0)        ? (1.0f - wy) : 0.0f;
            float wy1 = (y1 <= IMG_H-1)  ? wy          : 0.0f;
            float w00 = wx0 * wy0, w10 = wx1 * wy0;
            float w01 = wx0 * wy1, w11 = wx1 * wy1;

            int x0c = max(x0, 0);
            int x1c = min(x1, IMG_W - 1);
            int y0c = max(y0, 0);
            int y1c = min(y1, IMG_H - 1);

            // 4MB row-pair layout (L2-resident), pure u32 index math.
            uint32_t rowA = ((uint32_t)(y0c >> 1)) << 11;
            uint32_t rowB = ((uint32_t)(y1c >> 1)) << 11;
            uint32_t wA = pk[rowA + (uint32_t)x0c];
            uint32_t wB = pk[rowA + (uint32_t)x1c];
            uint32_t wC = pk[rowB + (uint32_t)x0c];
            uint32_t wD = pk[rowB + (uint32_t)x1c];
            uint32_t t00 = (y0c & 1) ? (wA >> 16) : (wA & 0xffffu);
            uint32_t t10 = (y0c & 1) ? (wB >> 16) : (wB & 0xffffu);
            uint32_t t01 = (y1c & 1) ? (wC >> 16) : (wC & 0xffffu);
            uint32_t t11 = (y1c & 1) ? (wD >> 16) : (wD & 0xffffu);

            // per-corner scaled weights for R(5b), G(6b), B(5b)
            float s0 = (float)(t00 >> 11) * w00 + (float)(t10 >> 11) * w10
                     + (float)(t01 >> 11) * w01 + (float)(t11 >> 11) * w11;
            float s1 = (float)((t00 >> 5) & 63u) * w00 + (float)((t10 >> 5) & 63u) * w10
                     + (float)((t01 >> 5) & 63u) * w01 + (float)((t11 >> 5) & 63u) * w11;
            float s2 = (float)(t00 & 31u) * w00 + (float)(t10 & 31u) * w10
                     + (float)(t01 & 31u) * w01 + (float)(t11 & 31u) * w11;
            s0 *= (1.0f / 31.0f);
            s1 *= (1.0f / 63.0f);
            s2 *= (1.0f / 31.0f);

            bool m = !((s0 == 0.0f) && (s1 == 0.0f) && (s2 == 0.0f));

            float d0 = s0 - r0;
            float d1 = s1 - r1;
            float d2 = s2 - r2;
            float per = sqrtf(d0*d0 + d1*d1 + d2*d2);

            accs[nb] += m ? per : 0.0f;
            cnl[nb]  += m ? 1.0f : 0.0f;
        }
    }

    // wave(64) shuffle reduce per batch, then LDS across 4 waves, then atomics
    __shared__ float lsum[4][NB], lcnt[4][NB];
    int wid = tid >> 6;
    int lane = tid & 63;
    #pragma unroll
    for (int nb = 0; nb < NB; ++nb) {
        float a = accs[nb], c = cnl[nb];
        #pragma unroll
        for (int off = 32; off > 0; off >>= 1) {
            a += __shfl_down(a, off, 64);
            c += __shfl_down(c, off, 64);
        }
        if (lane == 0) { lsum[wid][nb] = a; lcnt[wid][nb] = c; }
    }
    __syncthreads();
    if (tid < NB * 2) {
        int nb = tid & (NB - 1);
        int k = tid >> 2;   // 0 = sum, 1 = cnt  (NB=4)
        float v = 0.f;
        #pragma unroll
        for (int w = 0; w < 4; ++w) v += k ? lcnt[w][nb] : lsum[w][nb];
        atomicAdd(k ? &cnts[b0 + nb] : &sums[b0 + nb], v);
    }
}

__global__ void bsl_finalize(const float* __restrict__ sums,
                             const float* __restrict__ cnts,
                             float* __restrict__ out,
                             int B) {
    int b = threadIdx.x;  // 0..63
    float loss = 0.f;
    if (b < B) {
        loss = sums[b] / cnts[b];
        out[1 + b] = loss;
    }
    #pragma unroll
    for (int off = 32; off > 0; off >>= 1)
        loss += __shfl_down(loss, off, 64);
    if (b == 0) out[0] = loss;
}

extern "C" void kernel_launch(void* const* d_in, const int* in_sizes, int n_in,
                              void* d_out, int out_size, void* d_ws, size_t ws_size,
                              hipStream_t stream) {
    const float* xyz   = (const float*)d_in[0];
    const float* rgb   = (const float*)d_in[1];
    const float* img   = (const float*)d_in[2];
    const float* trans = (const float*)d_in[3];
    const float* yaw   = (const float*)d_in[4];
    const float* pitch = (const float*)d_in[5];
    const float* roll  = (const float*)d_in[6];
    float* out = (float*)d_out;

    const int n_pts = in_sizes[0] / 3;      // 200000
    const int B     = in_sizes[3] / 3;      // 32

    float* ws    = (float*)d_ws;
    float* rm    = ws;               // 9*B floats
    float* sums  = ws + 9 * B;       // B floats
    float* cnts  = ws + 10 * B;      // B floats
    uint32_t* hist = (uint32_t*)((char*)d_ws + HIST_OFF);
    uint16_t* key  = (uint16_t*)((char*)d_ws + KEY_OFF);
    uint32_t* pk   = (uint32_t*)((char*)d_ws + PK_OFF);
    float*    pts  = (float*)((char*)d_ws + PTS_OFF);

    hipMemsetAsync(hist, 0, NBINS * sizeof(uint32_t), stream);

    const int key_blocks = (n_pts + 255) / 256;   // 782
    bsl_pack_hist<<<4096 + key_blocks, 256, 0, stream>>>(
        img, pk, xyz, hist, key, yaw, pitch, roll, rm, sums, cnts, B, n_pts);

    bsl_scan<<<1, 256, 0, stream>>>(hist);

    bsl_scatter<<<key_blocks, 256, 0, stream>>>(xyz, rgb, key, hist, pts, n_pts);

    dim3 grid(key_blocks, B / NB);
    bsl_main<<<grid, 256, 0, stream>>>(pts, pk, trans, rm, sums, cnts, n_pts);

    bsl_finalize<<<1, 64, 0, stream>>>(sums, cnts, out, B);
}